// Round 7
// baseline (255.767 us; speedup 1.0000x reference)
//
#include <hip/hip_runtime.h>
#include <hip/hip_bf16.h>
#include <math.h>

// N=50000, E=800000, C=128, H=4, D=32, G=8 (group size 16).
#define CN 128
#define NBLK 256         // blocks in the fused prep scatter (full device)
#define BSH 8            // bucket = dst >> 8 (256 nodes/bucket); N<2^16 packs in int2
#define CAPSH 13         // per-bucket capacity in inter: 8192 slots (mean 4337, 58 sigma)

typedef __attribute__((ext_vector_type(8))) short bf16x8;
typedef __attribute__((ext_vector_type(4))) float f32x4;

// fp32 -> bf16 RTNE (bit trick; inputs are finite)
static __device__ inline unsigned int pack_bf16x2(float lo, float hi) {
    unsigned int ul = __float_as_uint(lo);
    unsigned int uh = __float_as_uint(hi);
    ul = (ul + 0x7fffu + ((ul >> 16) & 1u)) >> 16;
    uh = (uh + 0x7fffu + ((uh >> 16) & 1u)) & 0xffff0000u;
    return ul | uh;
}
static __device__ inline unsigned short bf16_of(float v) {
    unsigned int u = __float_as_uint(v);
    return (unsigned short)((u + 0x7fffu + ((u >> 16) & 1u)) >> 16);
}

// ---------------------------------------------------------------------------
// kprep: fused count+reserve+scatter. Per block: LDS histogram over its edge
// chunk -> one global atomicAdd per bucket to reserve a range in that bucket's
// fixed-CAP region of inter -> scatter via LDS cursors. Self-loops carry
// wbits=-1 sentinel; kbC substitutes ewmax. Tail blocks: W transposes + ce.
__global__ __launch_bounds__(256) void kprep(const int* __restrict__ srcs,
                                             const int* __restrict__ dsts,
                                             const float* __restrict__ ew,
                                             int e, int n,
                                             int* __restrict__ cursors,   // 256*16, zeroed
                                             int* __restrict__ ewmaxArr,
                                             int2* __restrict__ inter,
                                             const float* __restrict__ W0,
                                             const float* __restrict__ W1,
                                             const float* __restrict__ We0,
                                             const float* __restrict__ ae0,
                                             const float* __restrict__ We1,
                                             const float* __restrict__ ae1,
                                             unsigned short* __restrict__ wt0,
                                             unsigned short* __restrict__ wt1,
                                             float* __restrict__ ce) {
    __shared__ int lh[256];
    __shared__ int cur[256];
    __shared__ int wm[4];
    int t = threadIdx.x, blk = blockIdx.x;
    if (blk >= NBLK) {
        int b = blk - NBLK;
        if (b < 2) {
            const float* W = b ? W1 : W0;
            unsigned short* wt = b ? wt1 : wt0;
            for (int i = t; i < CN * CN; i += 256) {
                int k = i >> 7, c = i & 127;
                wt[c * CN + k] = bf16_of(W[k * CN + c]);
            }
        } else if (t < 8) {
            const float* We = (t < 4) ? We0 : We1;
            const float* ae = (t < 4) ? ae0 : ae1;
            int h = t & 3;
            float s = 0.f;
            for (int d = 0; d < 32; d++) s += We[h * 32 + d] * ae[h * 32 + d];
            ce[t] = s;
        }
        return;
    }
    lh[t] = 0;
    __syncthreads();
    int tot = e + n;
    int chunk = (tot + NBLK - 1) / NBLK;
    int start = blk * chunk, end = min(start + chunk, tot);
    float m = 0.f;
    for (int i = start + t; i < end; i += 256) {
        int d;
        if (i < e) { d = dsts[i]; m = fmaxf(m, ew[i]); }
        else       { d = i - e; }
        atomicAdd(&lh[d >> BSH], 1);
    }
#pragma unroll
    for (int off = 1; off < 64; off <<= 1) m = fmaxf(m, __shfl_xor(m, off));
    if ((t & 63) == 0) wm[t >> 6] = __float_as_int(m);   // ew >= 0: int order ok
    __syncthreads();
    int c = lh[t];
    cur[t] = c ? atomicAdd(&cursors[t * 16], c) : 0;
    if (t == 0)
        ewmaxArr[blk] = max(max(wm[0], wm[1]), max(wm[2], wm[3]));
    __syncthreads();
    for (int i = start + t; i < end; i += 256) {
        int sn, d, wbits;
        if (i < e) { sn = srcs[i]; d = dsts[i]; wbits = __float_as_int(ew[i]); }
        else       { sn = i - e;   d = sn;      wbits = -1; }
        int b = d >> BSH;
        int p = atomicAdd(&cur[b], 1);
        inter[((size_t)b << CAPSH) + p] = make_int2((d << 16) | sn, wbits);
    }
}

// ---------------------------------------------------------------------------
// kbC body: one block per bucket; builds rowptr + final CSR (4 B records:
// src | bf16(w)<<16). Bucket counts from final cursors; bases via LDS scan.
static __device__ void kbc_body(int* cnt, int* cur, int* wsum, int* bexc,
                                int* wmI, int b,
                                const int* __restrict__ cursors,
                                const int* __restrict__ ewmaxArr,
                                const int2* __restrict__ inter,
                                unsigned int* __restrict__ edges,
                                int* __restrict__ rowptr,
                                int n, int nb, int ep) {
    int t = threadIdx.x;
    int lane = t & 63, wid = t >> 6;
    if (t == 0) *wmI = 0;
    int v = cursors[t * 16];          // bucket t's edge count
    int s = v;
#pragma unroll
    for (int off = 1; off < 64; off <<= 1) {
        int u = __shfl_up(s, off);
        if (lane >= off) s += u;
    }
    int mi = ewmaxArr[t];
#pragma unroll
    for (int off = 1; off < 64; off <<= 1) mi = max(mi, __shfl_xor(mi, off));
    if (lane == 63) wsum[wid] = s;
    __syncthreads();                  // wmI=0 and wsum visible
    if (lane == 0) atomicMax(wmI, mi);
    int add = 0;
#pragma unroll
    for (int w = 0; w < 4; w++) if (w < wid) add += wsum[w];
    s += add;
    bexc[t] = s - v;                  // global CSR base of bucket t
    if (t == 255) bexc[256] = s;
    cnt[t] = 0;
    __syncthreads();                  // bexc/cnt ready; wmI final
    float wmax = __int_as_float(*wmI);
    int cntb = cursors[b * 16];
    size_t istart = (size_t)b << CAPSH;
    int gbase = bexc[b];
    for (int i = t; i < cntb; i += 256)
        atomicAdd(&cnt[(inter[istart + i].x >> 16) & 255], 1);
    __syncthreads();
    int v2 = cnt[t];
    int s2 = v2;
#pragma unroll
    for (int off = 1; off < 64; off <<= 1) {
        int u = __shfl_up(s2, off);
        if (lane >= off) s2 += u;
    }
    if (lane == 63) wsum[wid] = s2;
    __syncthreads();
    int wexcl = 0;
#pragma unroll
    for (int w = 0; w < 4; w++) if (w < wid) wexcl += wsum[w];
    int excl = wexcl + s2 - v2;
    int node = (b << BSH) + t;
    int gpos = gbase + excl;
    if (node < n) rowptr[node] = gpos;
    if (b == nb - 1 && t == 0) rowptr[n] = ep;
    cur[t] = gpos;
    __syncthreads();
    for (int i = t; i < cntb; i += 256) {
        int2 r = inter[istart + i];
        int p = atomicAdd(&cur[(r.x >> 16) & 255], 1);
        float w = (r.y == -1) ? wmax : __int_as_float(r.y);
        edges[p] = (unsigned int)(r.x & 0xffff) | ((unsigned int)bf16_of(w) << 16);
    }
}

// ---------------------------------------------------------------------------
// kgn body: fused GroupNorm + LeakyReLU(0.01) + MFMA GEMM + score dots
// (layer 0: fp32 x input). Weights read from L2-hot wt; LDS = 16 KB A-tile.
static __device__ void kgn_body(short* xs, int block_row,
                                const float* __restrict__ xin,
                                const float* __restrict__ gamma,
                                const float* __restrict__ beta,
                                const unsigned short* __restrict__ wt,
                                const float* __restrict__ asrc,
                                const float* __restrict__ adst,
                                unsigned int* __restrict__ hout,
                                float* __restrict__ ssrc,
                                float* __restrict__ sdst, int n) {
    int t = threadIdx.x;
    int lane = t & 63, w = t >> 6;
    int m = lane & 15, quad = lane >> 4;

    {
        int r = t & 63;
        int row = block_row + r;
        uint4* dst = (uint4*)xs;
#pragma unroll
        for (int u2 = 0; u2 < 2; u2++) {
            int g = (t >> 6) * 2 + u2;       // channel group 0..7 (k=16g..16g+15)
            uint4 lo, hi;
            if (row < n) {
                float v[16];
                const float4* xr = (const float4*)(xin + (size_t)row * CN + g * 16);
                float4 A = xr[0], B = xr[1], C = xr[2], D = xr[3];
                float tmp[16] = {A.x,A.y,A.z,A.w,B.x,B.y,B.z,B.w,
                                 C.x,C.y,C.z,C.w,D.x,D.y,D.z,D.w};
#pragma unroll
                for (int j = 0; j < 16; j++) v[j] = tmp[j];
                float mu = 0.f;
#pragma unroll
                for (int j = 0; j < 16; j++) mu += v[j];
                mu *= 0.0625f;
                float var = 0.f;
#pragma unroll
                for (int j = 0; j < 16; j++) { float d2 = v[j] - mu; var += d2 * d2; }
                var *= 0.0625f;
                float rsv = rsqrtf(var + 1e-5f);
                const float4* gp = (const float4*)(gamma + g * 16);
                const float4* bp = (const float4*)(beta + g * 16);
                float4 g0 = gp[0], g1 = gp[1], g2 = gp[2], g3 = gp[3];
                float4 b0 = bp[0], b1 = bp[1], b2 = bp[2], b3 = bp[3];
                float gv[16] = {g0.x,g0.y,g0.z,g0.w,g1.x,g1.y,g1.z,g1.w,
                                g2.x,g2.y,g2.z,g2.w,g3.x,g3.y,g3.z,g3.w};
                float bv[16] = {b0.x,b0.y,b0.z,b0.w,b1.x,b1.y,b1.z,b1.w,
                                b2.x,b2.y,b2.z,b2.w,b3.x,b3.y,b3.z,b3.w};
                float xn[16];
#pragma unroll
                for (int j = 0; j < 16; j++) {
                    float xv = (v[j] - mu) * rsv * gv[j] + bv[j];
                    xn[j] = xv > 0.f ? xv : 0.01f * xv;
                }
                lo = make_uint4(pack_bf16x2(xn[0], xn[1]),  pack_bf16x2(xn[2], xn[3]),
                                pack_bf16x2(xn[4], xn[5]),  pack_bf16x2(xn[6], xn[7]));
                hi = make_uint4(pack_bf16x2(xn[8], xn[9]),  pack_bf16x2(xn[10], xn[11]),
                                pack_bf16x2(xn[12], xn[13]), pack_bf16x2(xn[14], xn[15]));
            } else {
                lo = make_uint4(0, 0, 0, 0);
                hi = lo;
            }
            dst[r * 16 + ((2 * g)     ^ (r & 15))] = lo;
            dst[r * 16 + ((2 * g + 1) ^ (r & 15))] = hi;
        }
    }
    __syncthreads();

    f32x4 acc[4][2];
#pragma unroll
    for (int i = 0; i < 4; i++) { acc[i][0] = (f32x4)0.f; acc[i][1] = (f32x4)0.f; }

#pragma unroll
    for (int kc = 0; kc < 4; kc++) {
        int kb = 4 * kc + quad;
        bf16x8 af[4], bfr[2];
#pragma unroll
        for (int mt = 0; mt < 4; mt++)
            af[mt] = *(const bf16x8*)&xs[(16 * mt + m) * CN + ((kb ^ m) << 3)];
#pragma unroll
        for (int nt = 0; nt < 2; nt++) {
            int c = 32 * w + 16 * nt + m;
            bfr[nt] = *(const bf16x8*)&wt[c * CN + (kb << 3)];   // L2-hot, 16 B
        }
#pragma unroll
        for (int mt = 0; mt < 4; mt++) {
#pragma unroll
            for (int nt = 0; nt < 2; nt++)
                acc[mt][nt] = __builtin_amdgcn_mfma_f32_16x16x32_bf16(
                    af[mt], bfr[nt], acc[mt][nt], 0, 0, 0);
        }
    }

    float asv[2], adv[2];
#pragma unroll
    for (int nt = 0; nt < 2; nt++) {
        asv[nt] = asrc[32 * w + 16 * nt + m];
        adv[nt] = adst[32 * w + 16 * nt + m];
    }
#pragma unroll
    for (int mt = 0; mt < 4; mt++) {
#pragma unroll
        for (int j = 0; j < 4; j++) {
            float p = acc[mt][0][j] * asv[0] + acc[mt][1][j] * asv[1];
            float q = acc[mt][0][j] * adv[0] + acc[mt][1][j] * adv[1];
#pragma unroll
            for (int off = 1; off < 16; off <<= 1) {
                p += __shfl_xor(p, off);
                q += __shfl_xor(q, off);
            }
            if (m == 0) {
                int row = block_row + 16 * mt + 4 * quad + j;
                if (row < n) {
                    ssrc[row * 4 + w] = p;
                    sdst[row * 4 + w] = q;
                }
            }
        }
    }

    __syncthreads();
#pragma unroll
    for (int mt = 0; mt < 4; mt++) {
#pragma unroll
        for (int nt = 0; nt < 2; nt++) {
            int c = 32 * w + 16 * nt + m;
#pragma unroll
            for (int j = 0; j < 4; j++) {
                int rl = 16 * mt + 4 * quad + j;
                xs[rl * CN + c] = (short)bf16_of(acc[mt][nt][j]);
            }
        }
    }
    __syncthreads();
    {
        const uint4* src = (const uint4*)xs;
#pragma unroll
        for (int i = 0; i < 4; i++) {
            int u = t + 256 * i;
            int rl = u >> 4;
            int row = block_row + rl;
            if (row < n)
                *(uint4*)&hout[(size_t)row * 64 + ((u & 15) << 2)] = src[u];
        }
    }
}

// ---------------------------------------------------------------------------
// kbCgn: blocks [0,nb) run kbC; blocks [nb, nb+tiles) run layer-0 GN+GEMM.
__global__ __launch_bounds__(256, 4) void kbCgn(
        const int* __restrict__ cursors, const int* __restrict__ ewmaxArr,
        const int2* __restrict__ inter, unsigned int* __restrict__ edges,
        int* __restrict__ rowptr, int n, int nb, int ep,
        const float* __restrict__ xin, const float* __restrict__ gamma,
        const float* __restrict__ beta, const unsigned short* __restrict__ wt,
        const float* __restrict__ asrc, const float* __restrict__ adst,
        unsigned int* __restrict__ hout, float* __restrict__ ssrcO,
        float* __restrict__ sdstO) {
    __shared__ short xs[64 * CN];    // 16 KiB
    if ((int)blockIdx.x < nb) {
        int* cnt  = (int*)xs;             // ints, shorts [0..511]
        int* cur  = (int*)(xs + 512);     // shorts [512..1023]
        int* wsum = (int*)(xs + 1024);    // shorts [1024..1031]
        int* wmI  = (int*)(xs + 1040);    // shorts [1040..1041]
        int* bexc = (int*)(xs + 2048);    // shorts [2048..2561]
        kbc_body(cnt, cur, wsum, bexc, wmI, blockIdx.x,
                 cursors, ewmaxArr, inter, edges, rowptr, n, nb, ep);
        return;
    }
    kgn_body(xs, ((int)blockIdx.x - nb) * 64, xin,
             gamma, beta, wt, asrc, adst, hout, ssrcO, sdstO, n);
}

// ---------------------------------------------------------------------------
// kfuse: fused layer-0 aggregation + layer-1 GroupNorm + GEMM + score dots.
// One block = one 64-row tile: 16 node-quads run the proven kaggr3 gather
// loop; softmax output (fp32, + bias0) is group-normalized IN REGISTERS
// (group of 16 ch = 2 lanes, one shfl_xor(1) per stat), LeakyReLU'd, packed
// bf16 into the LDS tile; then the standard MFMA GEMM. Eliminates the x1b
// 25.6 MB round trip + a launch boundary; x1 stays fp32 into GN (closer to
// reference). Writes L1 outputs to separate buffers (hout2/ssrc2/sdst2) to
// avoid racing blocks still reading L0 data.
__global__ __launch_bounds__(256, 6) void kfuse(
        const uint4* __restrict__ h, const float* __restrict__ ssrc,
        const float* __restrict__ sdst, const int* __restrict__ rowptr,
        const unsigned int* __restrict__ edges, const float* __restrict__ ce4,
        const float* __restrict__ bias0,
        const float* __restrict__ gamma, const float* __restrict__ beta,
        const unsigned short* __restrict__ wt,
        const float* __restrict__ asrc, const float* __restrict__ adst,
        unsigned int* __restrict__ hout, float* __restrict__ ssrcO,
        float* __restrict__ sdstO, int n) {
    __shared__ short xs[64 * CN];    // 16 KiB
    int t = threadIdx.x;
    int lane = t & 63, w = t >> 6;
    int ll = lane & 15, g = lane >> 4;
    int head = ll >> 2;
    int block_row = blockIdx.x * 64;

    for (int q = 0; q < 16; q++) {
        int r = q * 4 + w;               // local tile row; whole wave same r
        int node = block_row + r;
        float a0=0.f,a1=0.f,a2=0.f,a3=0.f,a4=0.f,a5=0.f,a6=0.f,a7=0.f;
        float se = 0.f;
        if (node < n) {
            int start = rowptr[node], end = rowptr[node + 1];
            float sd = sdst[node * 4 + head];
            float ce = ce4[head];
            int i = start + g;
            for (; i + 12 < end; i += 16) {
                unsigned int er[4];
#pragma unroll
                for (int u = 0; u < 4; u++) er[u] = edges[i + 4 * u];
                float ssv[4]; uint4 U[4];
#pragma unroll
                for (int u = 0; u < 4; u++) {
                    int sidx = er[u] & 0xffff;
                    ssv[u] = ssrc[sidx * 4 + head];
                    U[u] = h[(size_t)sidx * 16 + ll];
                }
#pragma unroll
                for (int u = 0; u < 4; u++) {
                    float wv = __uint_as_float(er[u] & 0xffff0000u);
                    float l = ssv[u] + sd + wv * ce;
                    l = fmaxf(l, 0.2f * l);
                    float e = __expf(fminf(l, 80.f));
                    float h0 = __uint_as_float(U[u].x << 16);
                    float h1 = __uint_as_float(U[u].x & 0xffff0000u);
                    float h2 = __uint_as_float(U[u].y << 16);
                    float h3 = __uint_as_float(U[u].y & 0xffff0000u);
                    float h4 = __uint_as_float(U[u].z << 16);
                    float h5 = __uint_as_float(U[u].z & 0xffff0000u);
                    float h6 = __uint_as_float(U[u].w << 16);
                    float h7 = __uint_as_float(U[u].w & 0xffff0000u);
                    se += e;
                    a0 = fmaf(e, h0, a0); a1 = fmaf(e, h1, a1);
                    a2 = fmaf(e, h2, a2); a3 = fmaf(e, h3, a3);
                    a4 = fmaf(e, h4, a4); a5 = fmaf(e, h5, a5);
                    a6 = fmaf(e, h6, a6); a7 = fmaf(e, h7, a7);
                }
            }
            for (; i < end; i += 4) {
                unsigned int er = edges[i];
                int sidx = er & 0xffff;
                float ss = ssrc[sidx * 4 + head];
                uint4 U = h[(size_t)sidx * 16 + ll];
                float wv = __uint_as_float(er & 0xffff0000u);
                float l = ss + sd + wv * ce;
                l = fmaxf(l, 0.2f * l);
                float e = __expf(fminf(l, 80.f));
                float h0 = __uint_as_float(U.x << 16);
                float h1 = __uint_as_float(U.x & 0xffff0000u);
                float h2 = __uint_as_float(U.y << 16);
                float h3 = __uint_as_float(U.y & 0xffff0000u);
                float h4 = __uint_as_float(U.z << 16);
                float h5 = __uint_as_float(U.z & 0xffff0000u);
                float h6 = __uint_as_float(U.w << 16);
                float h7 = __uint_as_float(U.w & 0xffff0000u);
                se += e;
                a0 = fmaf(e, h0, a0); a1 = fmaf(e, h1, a1);
                a2 = fmaf(e, h2, a2); a3 = fmaf(e, h3, a3);
                a4 = fmaf(e, h4, a4); a5 = fmaf(e, h5, a5);
                a6 = fmaf(e, h6, a6); a7 = fmaf(e, h7, a7);
            }
#pragma unroll
            for (int off = 16; off < 64; off <<= 1) {
                a0 += __shfl_xor(a0, off); a1 += __shfl_xor(a1, off);
                a2 += __shfl_xor(a2, off); a3 += __shfl_xor(a3, off);
                a4 += __shfl_xor(a4, off); a5 += __shfl_xor(a5, off);
                a6 += __shfl_xor(a6, off); a7 += __shfl_xor(a7, off);
                se += __shfl_xor(se, off);
            }
        }
        if (g == 0) {   // lanes 0..15 of each wave: GN + pack + LDS write
            uint4 P = make_uint4(0, 0, 0, 0);
            if (node < n) {
                float inv = 1.f / (se + 1e-16f);
                const float4* bp = (const float4*)(bias0 + ll * 8);
                float4 bb0 = bp[0], bb1 = bp[1];
                float o0 = a0 * inv + bb0.x, o1 = a1 * inv + bb0.y;
                float o2 = a2 * inv + bb0.z, o3 = a3 * inv + bb0.w;
                float o4 = a4 * inv + bb1.x, o5 = a5 * inv + bb1.y;
                float o6 = a6 * inv + bb1.z, o7 = a7 * inv + bb1.w;
                float ps = o0 + o1 + o2 + o3 + o4 + o5 + o6 + o7;
                ps += __shfl_xor(ps, 1);
                float mu = ps * 0.0625f;
                float d0 = o0 - mu, d1 = o1 - mu, d2 = o2 - mu, d3 = o3 - mu;
                float d4 = o4 - mu, d5 = o5 - mu, d6 = o6 - mu, d7 = o7 - mu;
                float v2 = d0*d0 + d1*d1 + d2*d2 + d3*d3
                         + d4*d4 + d5*d5 + d6*d6 + d7*d7;
                v2 += __shfl_xor(v2, 1);
                float rsv = rsqrtf(v2 * 0.0625f + 1e-5f);
                const float4* gp = (const float4*)(gamma + ll * 8);
                const float4* bq = (const float4*)(beta + ll * 8);
                float4 g0 = gp[0], g1 = gp[1], be0 = bq[0], be1 = bq[1];
                float x0 = d0 * rsv * g0.x + be0.x, x1 = d1 * rsv * g0.y + be0.y;
                float x2 = d2 * rsv * g0.z + be0.z, x3 = d3 * rsv * g0.w + be0.w;
                float x4 = d4 * rsv * g1.x + be1.x, x5 = d5 * rsv * g1.y + be1.y;
                float x6 = d6 * rsv * g1.z + be1.z, x7 = d7 * rsv * g1.w + be1.w;
                x0 = x0 > 0.f ? x0 : 0.01f * x0;  x1 = x1 > 0.f ? x1 : 0.01f * x1;
                x2 = x2 > 0.f ? x2 : 0.01f * x2;  x3 = x3 > 0.f ? x3 : 0.01f * x3;
                x4 = x4 > 0.f ? x4 : 0.01f * x4;  x5 = x5 > 0.f ? x5 : 0.01f * x5;
                x6 = x6 > 0.f ? x6 : 0.01f * x6;  x7 = x7 > 0.f ? x7 : 0.01f * x7;
                P = make_uint4(pack_bf16x2(x0, x1), pack_bf16x2(x2, x3),
                               pack_bf16x2(x4, x5), pack_bf16x2(x6, x7));
            }
            ((uint4*)xs)[r * 16 + (ll ^ (r & 15))] = P;
        }
    }
    __syncthreads();

    // ---- GEMM phase (identical to kgn_body's) ----
    int m = ll, quad = g;
    f32x4 acc[4][2];
#pragma unroll
    for (int i = 0; i < 4; i++) { acc[i][0] = (f32x4)0.f; acc[i][1] = (f32x4)0.f; }
#pragma unroll
    for (int kc = 0; kc < 4; kc++) {
        int kb = 4 * kc + quad;
        bf16x8 af[4], bfr[2];
#pragma unroll
        for (int mt = 0; mt < 4; mt++)
            af[mt] = *(const bf16x8*)&xs[(16 * mt + m) * CN + ((kb ^ m) << 3)];
#pragma unroll
        for (int nt = 0; nt < 2; nt++) {
            int c = 32 * w + 16 * nt + m;
            bfr[nt] = *(const bf16x8*)&wt[c * CN + (kb << 3)];
        }
#pragma unroll
        for (int mt = 0; mt < 4; mt++) {
#pragma unroll
            for (int nt = 0; nt < 2; nt++)
                acc[mt][nt] = __builtin_amdgcn_mfma_f32_16x16x32_bf16(
                    af[mt], bfr[nt], acc[mt][nt], 0, 0, 0);
        }
    }
    float asv[2], adv[2];
#pragma unroll
    for (int nt = 0; nt < 2; nt++) {
        asv[nt] = asrc[32 * w + 16 * nt + m];
        adv[nt] = adst[32 * w + 16 * nt + m];
    }
#pragma unroll
    for (int mt = 0; mt < 4; mt++) {
#pragma unroll
        for (int j = 0; j < 4; j++) {
            float p = acc[mt][0][j] * asv[0] + acc[mt][1][j] * asv[1];
            float q2 = acc[mt][0][j] * adv[0] + acc[mt][1][j] * adv[1];
#pragma unroll
            for (int off = 1; off < 16; off <<= 1) {
                p += __shfl_xor(p, off);
                q2 += __shfl_xor(q2, off);
            }
            if (m == 0) {
                int row = block_row + 16 * mt + 4 * quad + j;
                if (row < n) {
                    ssrcO[row * 4 + w] = p;
                    sdstO[row * 4 + w] = q2;
                }
            }
        }
    }
    __syncthreads();
#pragma unroll
    for (int mt = 0; mt < 4; mt++) {
#pragma unroll
        for (int nt = 0; nt < 2; nt++) {
            int c = 32 * w + 16 * nt + m;
#pragma unroll
            for (int j = 0; j < 4; j++) {
                int rl = 16 * mt + 4 * quad + j;
                xs[rl * CN + c] = (short)bf16_of(acc[mt][nt][j]);
            }
        }
    }
    __syncthreads();
    {
        const uint4* src = (const uint4*)xs;
#pragma unroll
        for (int i = 0; i < 4; i++) {
            int u = t + 256 * i;
            int rl = u >> 4;
            int row = block_row + rl;
            if (row < n)
                *(uint4*)&hout[(size_t)row * 64 + ((u & 15) << 2)] = src[u];
        }
    }
}

// ---------------------------------------------------------------------------
// kaggr3: single-pass softmax aggregation (final layer, fp32 out).
__global__ __launch_bounds__(256, 8) void kaggr3(
        const uint4* __restrict__ h, const float* __restrict__ ssrc,
        const float* __restrict__ sdst, const int* __restrict__ rowptr,
        const unsigned int* __restrict__ edges, const float* __restrict__ ce4,
        const float* __restrict__ bias, float* __restrict__ out, int n) {
    int t = threadIdx.x;
    int node = blockIdx.x * 4 + (t >> 6);
    if (node >= n) return;
    int l64 = t & 63;
    int ll = l64 & 15;
    int g  = l64 >> 4;
    int head = ll >> 2;

    int start = rowptr[node], end = rowptr[node + 1];
    float sd = sdst[node * 4 + head];
    float ce = ce4[head];

    float a0=0.f,a1=0.f,a2=0.f,a3=0.f,a4=0.f,a5=0.f,a6=0.f,a7=0.f;
    float se = 0.f;

    int i = start + g;
    for (; i + 12 < end; i += 16) {
        unsigned int er[4];
#pragma unroll
        for (int u = 0; u < 4; u++) er[u] = edges[i + 4 * u];
        float ssv[4]; uint4 U[4];
#pragma unroll
        for (int u = 0; u < 4; u++) {
            int sidx = er[u] & 0xffff;
            ssv[u] = ssrc[sidx * 4 + head];
            U[u] = h[(size_t)sidx * 16 + ll];
        }
#pragma unroll
        for (int u = 0; u < 4; u++) {
            float wv = __uint_as_float(er[u] & 0xffff0000u);
            float l = ssv[u] + sd + wv * ce;
            l = fmaxf(l, 0.2f * l);
            float e = __expf(fminf(l, 80.f));
            float h0 = __uint_as_float(U[u].x << 16);
            float h1 = __uint_as_float(U[u].x & 0xffff0000u);
            float h2 = __uint_as_float(U[u].y << 16);
            float h3 = __uint_as_float(U[u].y & 0xffff0000u);
            float h4 = __uint_as_float(U[u].z << 16);
            float h5 = __uint_as_float(U[u].z & 0xffff0000u);
            float h6 = __uint_as_float(U[u].w << 16);
            float h7 = __uint_as_float(U[u].w & 0xffff0000u);
            se += e;
            a0 = fmaf(e, h0, a0); a1 = fmaf(e, h1, a1);
            a2 = fmaf(e, h2, a2); a3 = fmaf(e, h3, a3);
            a4 = fmaf(e, h4, a4); a5 = fmaf(e, h5, a5);
            a6 = fmaf(e, h6, a6); a7 = fmaf(e, h7, a7);
        }
    }
    for (; i < end; i += 4) {
        unsigned int er = edges[i];
        int sidx = er & 0xffff;
        float ss = ssrc[sidx * 4 + head];
        uint4 U = h[(size_t)sidx * 16 + ll];
        float wv = __uint_as_float(er & 0xffff0000u);
        float l = ss + sd + wv * ce;
        l = fmaxf(l, 0.2f * l);
        float e = __expf(fminf(l, 80.f));
        float h0 = __uint_as_float(U.x << 16);
        float h1 = __uint_as_float(U.x & 0xffff0000u);
        float h2 = __uint_as_float(U.y << 16);
        float h3 = __uint_as_float(U.y & 0xffff0000u);
        float h4 = __uint_as_float(U.z << 16);
        float h5 = __uint_as_float(U.z & 0xffff0000u);
        float h6 = __uint_as_float(U.w << 16);
        float h7 = __uint_as_float(U.w & 0xffff0000u);
        se += e;
        a0 = fmaf(e, h0, a0); a1 = fmaf(e, h1, a1);
        a2 = fmaf(e, h2, a2); a3 = fmaf(e, h3, a3);
        a4 = fmaf(e, h4, a4); a5 = fmaf(e, h5, a5);
        a6 = fmaf(e, h6, a6); a7 = fmaf(e, h7, a7);
    }
#pragma unroll
    for (int off = 16; off < 64; off <<= 1) {
        a0 += __shfl_xor(a0, off); a1 += __shfl_xor(a1, off);
        a2 += __shfl_xor(a2, off); a3 += __shfl_xor(a3, off);
        a4 += __shfl_xor(a4, off); a5 += __shfl_xor(a5, off);
        a6 += __shfl_xor(a6, off); a7 += __shfl_xor(a7, off);
        se += __shfl_xor(se, off);
    }
    if (g == 0) {
        float inv = 1.f / (se + 1e-16f);
        const float4* bp = (const float4*)(bias + ll * 8);
        float4 b0 = bp[0], b1 = bp[1];
        float o0 = a0 * inv + b0.x, o1 = a1 * inv + b0.y;
        float o2 = a2 * inv + b0.z, o3 = a3 * inv + b0.w;
        float o4 = a4 * inv + b1.x, o5 = a5 * inv + b1.y;
        float o6 = a6 * inv + b1.z, o7 = a7 * inv + b1.w;
        float4* orow = (float4*)(out + (size_t)node * CN + ll * 8);
        orow[0] = make_float4(o0, o1, o2, o3);
        orow[1] = make_float4(o4, o5, o6, o7);
    }
}

// ---------------------------------------------------------------------------
extern "C" void kernel_launch(void* const* d_in, const int* in_sizes, int n_in,
                              void* d_out, int out_size, void* d_ws, size_t ws_size,
                              hipStream_t stream) {
    const float* x  = (const float*)d_in[0];
    const int*   ei = (const int*)d_in[1];
    const float* ew = (const float*)d_in[2];
    int N_ = in_sizes[0] / CN;
    int E_ = in_sizes[2];
    int EP = E_ + N_;
    int NB = (N_ + 255) >> BSH;
    int NT = (N_ + 63) / 64;

    size_t off = 0;
    auto alloc = [&](size_t bytes) -> void* {
        void* p = (char*)d_ws + off;
        off += (bytes + 255) & ~(size_t)255;
        return p;
    };
    unsigned int* hbuf  = (unsigned int*)alloc((size_t)N_ * 64 * 4);  // L0 h (bf16x2)
    unsigned int* hbuf2 = (unsigned int*)alloc((size_t)N_ * 64 * 4);  // L1 h (bf16x2)
    float* ssrc    = (float*)alloc((size_t)N_ * 4 * 4);
    float* sdst    = (float*)alloc((size_t)N_ * 4 * 4);
    float* ssrc2   = (float*)alloc((size_t)N_ * 4 * 4);
    float* sdst2   = (float*)alloc((size_t)N_ * 4 * 4);
    int*   rowptr  = (int*)alloc((size_t)(N_ + 1) * 4);
    unsigned int* edges = (unsigned int*)alloc((size_t)EP * 4);
    int2*  inter   = (int2*)alloc((size_t)256 << CAPSH << 3);        // 16.8 MB
    int*   cursors = (int*)alloc((size_t)256 * 16 * 4);              // line-strided
    int*   ewmaxArr= (int*)alloc((size_t)NBLK * 4);
    unsigned short* wt0 = (unsigned short*)alloc((size_t)CN * CN * 2);
    unsigned short* wt1 = (unsigned short*)alloc((size_t)CN * CN * 2);
    float* cedge   = (float*)alloc(256);

    hipMemsetAsync(cursors, 0, (size_t)256 * 16 * 4, stream);

    const int* srcs = ei;
    const int* dsts = ei + E_;

    kprep<<<NBLK + 3, 256, 0, stream>>>(srcs, dsts, ew, E_, N_, cursors, ewmaxArr,
                                        inter,
                                        (const float*)d_in[5], (const float*)d_in[13],
                                        (const float*)d_in[6], (const float*)d_in[9],
                                        (const float*)d_in[14], (const float*)d_in[17],
                                        wt0, wt1, cedge);

    // merged: kbC (blocks [0,NB)) + layer-0 GN/GEMM (blocks [NB, NB+NT))
    kbCgn<<<NB + NT, 256, 0, stream>>>(
        cursors, ewmaxArr, inter, edges, rowptr, N_, NB, EP,
        x, (const float*)d_in[3], (const float*)d_in[4], wt0,
        (const float*)d_in[7], (const float*)d_in[8],
        hbuf, ssrc, sdst);

    // fused: layer-0 aggregation + layer-1 GN/GEMM
    kfuse<<<NT, 256, 0, stream>>>(
        (const uint4*)hbuf, ssrc, sdst, rowptr, edges, cedge,
        (const float*)d_in[10],
        (const float*)d_in[11], (const float*)d_in[12], wt1,
        (const float*)d_in[15], (const float*)d_in[16],
        hbuf2, ssrc2, sdst2, N_);

    // final: layer-1 aggregation -> fp32 output
    kaggr3<<<(N_ + 3) / 4, 256, 0, stream>>>(
        (const uint4*)hbuf2, ssrc2, sdst2, rowptr, edges, cedge + 4,
        (const float*)d_in[18], (float*)d_out, N_);
}

// Round 8
// 247.003 us; speedup vs baseline: 1.0355x; 1.0355x over previous
//
#include <hip/hip_runtime.h>
#include <hip/hip_bf16.h>
#include <math.h>

// N=50000, E=800000, C=128, H=4, D=32, G=8 (group size 16).
#define CN 128
#define NBLK 256         // blocks in the fused prep scatter (full device)
#define BSH 8            // bucket = dst >> 8 (256 nodes/bucket); N<2^16 packs in int2
#define CAPSH 13         // per-bucket capacity in inter: 8192 slots (mean 4337, 58 sigma)

typedef __attribute__((ext_vector_type(8))) short bf16x8;
typedef __attribute__((ext_vector_type(4))) float f32x4;

// fp32 -> bf16 RTNE (bit trick; inputs are finite)
static __device__ inline unsigned int pack_bf16x2(float lo, float hi) {
    unsigned int ul = __float_as_uint(lo);
    unsigned int uh = __float_as_uint(hi);
    ul = (ul + 0x7fffu + ((ul >> 16) & 1u)) >> 16;
    uh = (uh + 0x7fffu + ((uh >> 16) & 1u)) & 0xffff0000u;
    return ul | uh;
}
static __device__ inline unsigned short bf16_of(float v) {
    unsigned int u = __float_as_uint(v);
    return (unsigned short)((u + 0x7fffu + ((u >> 16) & 1u)) >> 16);
}

// ---------------------------------------------------------------------------
// kprep: fused count+reserve+scatter. Per block: LDS histogram over its edge
// chunk -> one global atomicAdd per bucket to reserve a range in that bucket's
// fixed-CAP region of inter -> scatter via LDS cursors. Self-loops carry
// wbits=-1 sentinel; kbC substitutes ewmax. Tail blocks: W transposes + ce.
__global__ __launch_bounds__(256) void kprep(const int* __restrict__ srcs,
                                             const int* __restrict__ dsts,
                                             const float* __restrict__ ew,
                                             int e, int n,
                                             int* __restrict__ cursors,   // 256*16, zeroed
                                             int* __restrict__ ewmaxArr,
                                             int2* __restrict__ inter,
                                             const float* __restrict__ W0,
                                             const float* __restrict__ W1,
                                             const float* __restrict__ We0,
                                             const float* __restrict__ ae0,
                                             const float* __restrict__ We1,
                                             const float* __restrict__ ae1,
                                             unsigned short* __restrict__ wt0,
                                             unsigned short* __restrict__ wt1,
                                             float* __restrict__ ce) {
    __shared__ int lh[256];
    __shared__ int cur[256];
    __shared__ int wm[4];
    int t = threadIdx.x, blk = blockIdx.x;
    if (blk >= NBLK) {
        int b = blk - NBLK;
        if (b < 2) {
            const float* W = b ? W1 : W0;
            unsigned short* wt = b ? wt1 : wt0;
            for (int i = t; i < CN * CN; i += 256) {
                int k = i >> 7, c = i & 127;
                wt[c * CN + k] = bf16_of(W[k * CN + c]);
            }
        } else if (t < 8) {
            const float* We = (t < 4) ? We0 : We1;
            const float* ae = (t < 4) ? ae0 : ae1;
            int h = t & 3;
            float s = 0.f;
            for (int d = 0; d < 32; d++) s += We[h * 32 + d] * ae[h * 32 + d];
            ce[t] = s;
        }
        return;
    }
    lh[t] = 0;
    __syncthreads();
    int tot = e + n;
    int chunk = (tot + NBLK - 1) / NBLK;
    int start = blk * chunk, end = min(start + chunk, tot);
    float m = 0.f;
    for (int i = start + t; i < end; i += 256) {
        int d;
        if (i < e) { d = dsts[i]; m = fmaxf(m, ew[i]); }
        else       { d = i - e; }
        atomicAdd(&lh[d >> BSH], 1);
    }
#pragma unroll
    for (int off = 1; off < 64; off <<= 1) m = fmaxf(m, __shfl_xor(m, off));
    if ((t & 63) == 0) wm[t >> 6] = __float_as_int(m);   // ew >= 0: int order ok
    __syncthreads();
    int c = lh[t];
    cur[t] = c ? atomicAdd(&cursors[t * 16], c) : 0;
    if (t == 0)
        ewmaxArr[blk] = max(max(wm[0], wm[1]), max(wm[2], wm[3]));
    __syncthreads();
    for (int i = start + t; i < end; i += 256) {
        int sn, d, wbits;
        if (i < e) { sn = srcs[i]; d = dsts[i]; wbits = __float_as_int(ew[i]); }
        else       { sn = i - e;   d = sn;      wbits = -1; }
        int b = d >> BSH;
        int p = atomicAdd(&cur[b], 1);
        inter[((size_t)b << CAPSH) + p] = make_int2((d << 16) | sn, wbits);
    }
}

// ---------------------------------------------------------------------------
// kbC body: one block per bucket; builds rowptr + final CSR (4 B records:
// src | bf16(w)<<16). Bucket counts from final cursors; bases via LDS scan.
static __device__ void kbc_body(int* cnt, int* cur, int* wsum, int* bexc,
                                int* wmI, int b,
                                const int* __restrict__ cursors,
                                const int* __restrict__ ewmaxArr,
                                const int2* __restrict__ inter,
                                unsigned int* __restrict__ edges,
                                int* __restrict__ rowptr,
                                int n, int nb, int ep) {
    int t = threadIdx.x;
    int lane = t & 63, wid = t >> 6;
    if (t == 0) *wmI = 0;
    int v = cursors[t * 16];          // bucket t's edge count
    int s = v;
#pragma unroll
    for (int off = 1; off < 64; off <<= 1) {
        int u = __shfl_up(s, off);
        if (lane >= off) s += u;
    }
    int mi = ewmaxArr[t];
#pragma unroll
    for (int off = 1; off < 64; off <<= 1) mi = max(mi, __shfl_xor(mi, off));
    if (lane == 63) wsum[wid] = s;
    __syncthreads();                  // wmI=0 and wsum visible
    if (lane == 0) atomicMax(wmI, mi);
    int add = 0;
#pragma unroll
    for (int w = 0; w < 4; w++) if (w < wid) add += wsum[w];
    s += add;
    bexc[t] = s - v;                  // global CSR base of bucket t
    if (t == 255) bexc[256] = s;
    cnt[t] = 0;
    __syncthreads();                  // bexc/cnt ready; wmI final
    float wmax = __int_as_float(*wmI);
    int cntb = cursors[b * 16];
    size_t istart = (size_t)b << CAPSH;
    int gbase = bexc[b];
    for (int i = t; i < cntb; i += 256)
        atomicAdd(&cnt[(inter[istart + i].x >> 16) & 255], 1);
    __syncthreads();
    int v2 = cnt[t];
    int s2 = v2;
#pragma unroll
    for (int off = 1; off < 64; off <<= 1) {
        int u = __shfl_up(s2, off);
        if (lane >= off) s2 += u;
    }
    if (lane == 63) wsum[wid] = s2;
    __syncthreads();
    int wexcl = 0;
#pragma unroll
    for (int w = 0; w < 4; w++) if (w < wid) wexcl += wsum[w];
    int excl = wexcl + s2 - v2;
    int node = (b << BSH) + t;
    int gpos = gbase + excl;
    if (node < n) rowptr[node] = gpos;
    if (b == nb - 1 && t == 0) rowptr[n] = ep;
    cur[t] = gpos;
    __syncthreads();
    for (int i = t; i < cntb; i += 256) {
        int2 r = inter[istart + i];
        int p = atomicAdd(&cur[(r.x >> 16) & 255], 1);
        float w = (r.y == -1) ? wmax : __int_as_float(r.y);
        edges[p] = (unsigned int)(r.x & 0xffff) | ((unsigned int)bf16_of(w) << 16);
    }
}

// ---------------------------------------------------------------------------
// kgn body: fused GroupNorm + LeakyReLU(0.01) + MFMA GEMM + score dots.
// B-operand (weights, 32 KB, shared by all blocks) read directly from the
// L2-hot transposed wt table — LDS = 16 KB A-tile only, 4 blocks/CU.
static __device__ void kgn_body(short* xs, int block_row,
                                const float* __restrict__ xin,
                                const uint4* __restrict__ xin_b,
                                int inbf16, const float* __restrict__ gamma,
                                const float* __restrict__ beta,
                                const unsigned short* __restrict__ wt,
                                const float* __restrict__ asrc,
                                const float* __restrict__ adst,
                                unsigned int* __restrict__ hout,
                                float* __restrict__ ssrc,
                                float* __restrict__ sdst, int n) {
    int t = threadIdx.x;
    int lane = t & 63, w = t >> 6;
    int m = lane & 15, quad = lane >> 4;

    {
        int r = t & 63;
        int row = block_row + r;
        uint4* dst = (uint4*)xs;
#pragma unroll
        for (int u2 = 0; u2 < 2; u2++) {
            int g = (t >> 6) * 2 + u2;       // channel group 0..7 (k=16g..16g+15)
            uint4 lo, hi;
            if (row < n) {
                float v[16];
                if (inbf16) {
                    uint4 A = xin_b[(size_t)row * 16 + g * 2];
                    uint4 B = xin_b[(size_t)row * 16 + g * 2 + 1];
                    unsigned int uu[8] = {A.x,A.y,A.z,A.w,B.x,B.y,B.z,B.w};
#pragma unroll
                    for (int j = 0; j < 8; j++) {
                        v[2*j]   = __uint_as_float(uu[j] << 16);
                        v[2*j+1] = __uint_as_float(uu[j] & 0xffff0000u);
                    }
                } else {
                    const float4* xr = (const float4*)(xin + (size_t)row * CN + g * 16);
                    float4 A = xr[0], B = xr[1], C = xr[2], D = xr[3];
                    float tmp[16] = {A.x,A.y,A.z,A.w,B.x,B.y,B.z,B.w,
                                     C.x,C.y,C.z,C.w,D.x,D.y,D.z,D.w};
#pragma unroll
                    for (int j = 0; j < 16; j++) v[j] = tmp[j];
                }
                float mu = 0.f;
#pragma unroll
                for (int j = 0; j < 16; j++) mu += v[j];
                mu *= 0.0625f;
                float var = 0.f;
#pragma unroll
                for (int j = 0; j < 16; j++) { float d2 = v[j] - mu; var += d2 * d2; }
                var *= 0.0625f;
                float rsv = rsqrtf(var + 1e-5f);
                const float4* gp = (const float4*)(gamma + g * 16);
                const float4* bp = (const float4*)(beta + g * 16);
                float4 g0 = gp[0], g1 = gp[1], g2 = gp[2], g3 = gp[3];
                float4 b0 = bp[0], b1 = bp[1], b2 = bp[2], b3 = bp[3];
                float gv[16] = {g0.x,g0.y,g0.z,g0.w,g1.x,g1.y,g1.z,g1.w,
                                g2.x,g2.y,g2.z,g2.w,g3.x,g3.y,g3.z,g3.w};
                float bv[16] = {b0.x,b0.y,b0.z,b0.w,b1.x,b1.y,b1.z,b1.w,
                                b2.x,b2.y,b2.z,b2.w,b3.x,b3.y,b3.z,b3.w};
                float xn[16];
#pragma unroll
                for (int j = 0; j < 16; j++) {
                    float xv = (v[j] - mu) * rsv * gv[j] + bv[j];
                    xn[j] = xv > 0.f ? xv : 0.01f * xv;
                }
                lo = make_uint4(pack_bf16x2(xn[0], xn[1]),  pack_bf16x2(xn[2], xn[3]),
                                pack_bf16x2(xn[4], xn[5]),  pack_bf16x2(xn[6], xn[7]));
                hi = make_uint4(pack_bf16x2(xn[8], xn[9]),  pack_bf16x2(xn[10], xn[11]),
                                pack_bf16x2(xn[12], xn[13]), pack_bf16x2(xn[14], xn[15]));
            } else {
                lo = make_uint4(0, 0, 0, 0);
                hi = lo;
            }
            dst[r * 16 + ((2 * g)     ^ (r & 15))] = lo;
            dst[r * 16 + ((2 * g + 1) ^ (r & 15))] = hi;
        }
    }
    __syncthreads();

    f32x4 acc[4][2];
#pragma unroll
    for (int i = 0; i < 4; i++) { acc[i][0] = (f32x4)0.f; acc[i][1] = (f32x4)0.f; }

#pragma unroll
    for (int kc = 0; kc < 4; kc++) {
        int kb = 4 * kc + quad;
        bf16x8 af[4], bfr[2];
#pragma unroll
        for (int mt = 0; mt < 4; mt++)
            af[mt] = *(const bf16x8*)&xs[(16 * mt + m) * CN + ((kb ^ m) << 3)];
#pragma unroll
        for (int nt = 0; nt < 2; nt++) {
            int c = 32 * w + 16 * nt + m;
            bfr[nt] = *(const bf16x8*)&wt[c * CN + (kb << 3)];   // L2-hot, 16 B
        }
#pragma unroll
        for (int mt = 0; mt < 4; mt++) {
#pragma unroll
            for (int nt = 0; nt < 2; nt++)
                acc[mt][nt] = __builtin_amdgcn_mfma_f32_16x16x32_bf16(
                    af[mt], bfr[nt], acc[mt][nt], 0, 0, 0);
        }
    }

    float asv[2], adv[2];
#pragma unroll
    for (int nt = 0; nt < 2; nt++) {
        asv[nt] = asrc[32 * w + 16 * nt + m];
        adv[nt] = adst[32 * w + 16 * nt + m];
    }
#pragma unroll
    for (int mt = 0; mt < 4; mt++) {
#pragma unroll
        for (int j = 0; j < 4; j++) {
            float p = acc[mt][0][j] * asv[0] + acc[mt][1][j] * asv[1];
            float q = acc[mt][0][j] * adv[0] + acc[mt][1][j] * adv[1];
#pragma unroll
            for (int off = 1; off < 16; off <<= 1) {
                p += __shfl_xor(p, off);
                q += __shfl_xor(q, off);
            }
            if (m == 0) {
                int row = block_row + 16 * mt + 4 * quad + j;
                if (row < n) {
                    ssrc[row * 4 + w] = p;
                    sdst[row * 4 + w] = q;
                }
            }
        }
    }

    __syncthreads();
#pragma unroll
    for (int mt = 0; mt < 4; mt++) {
#pragma unroll
        for (int nt = 0; nt < 2; nt++) {
            int c = 32 * w + 16 * nt + m;
#pragma unroll
            for (int j = 0; j < 4; j++) {
                int rl = 16 * mt + 4 * quad + j;
                xs[rl * CN + c] = (short)bf16_of(acc[mt][nt][j]);
            }
        }
    }
    __syncthreads();
    {
        const uint4* src = (const uint4*)xs;
#pragma unroll
        for (int i = 0; i < 4; i++) {
            int u = t + 256 * i;
            int rl = u >> 4;
            int row = block_row + rl;
            if (row < n)
                *(uint4*)&hout[(size_t)row * 64 + ((u & 15) << 2)] = src[u];
        }
    }
}

// ---------------------------------------------------------------------------
// kbCgn: blocks [0,nb) run kbC; blocks [nb, nb+tiles) run layer-0 GN+GEMM.
__global__ __launch_bounds__(256, 4) void kbCgn(
        const int* __restrict__ cursors, const int* __restrict__ ewmaxArr,
        const int2* __restrict__ inter, unsigned int* __restrict__ edges,
        int* __restrict__ rowptr, int n, int nb, int ep,
        const float* __restrict__ xin, const float* __restrict__ gamma,
        const float* __restrict__ beta, const unsigned short* __restrict__ wt,
        const float* __restrict__ asrc, const float* __restrict__ adst,
        unsigned int* __restrict__ hout, float* __restrict__ ssrcO,
        float* __restrict__ sdstO) {
    __shared__ short xs[64 * CN];    // 16 KiB
    if ((int)blockIdx.x < nb) {
        int* cnt  = (int*)xs;             // ints, shorts [0..511]
        int* cur  = (int*)(xs + 512);     // shorts [512..1023]
        int* wsum = (int*)(xs + 1024);    // shorts [1024..1031]
        int* wmI  = (int*)(xs + 1040);    // shorts [1040..1041]
        int* bexc = (int*)(xs + 2048);    // shorts [2048..2561]
        kbc_body(cnt, cur, wsum, bexc, wmI, blockIdx.x,
                 cursors, ewmaxArr, inter, edges, rowptr, n, nb, ep);
        return;
    }
    kgn_body(xs, ((int)blockIdx.x - nb) * 64, xin, (const uint4*)0, 0,
             gamma, beta, wt, asrc, adst, hout, ssrcO, sdstO, n);
}

// Standalone GN+GEMM (layer 1, bf16 input path).
__global__ __launch_bounds__(256, 4) void kgn_gemm7(
        const float* __restrict__ xin, const uint4* __restrict__ xin_b,
        int inbf16, const float* __restrict__ gamma,
        const float* __restrict__ beta, const unsigned short* __restrict__ wt,
        const float* __restrict__ asrc, const float* __restrict__ adst,
        unsigned int* __restrict__ hout, float* __restrict__ ssrc,
        float* __restrict__ sdst, int n) {
    __shared__ short xs[64 * CN];    // 16 KiB
    kgn_body(xs, blockIdx.x * 64, xin, xin_b, inbf16,
             gamma, beta, wt, asrc, adst, hout, ssrc, sdst, n);
}

// ---------------------------------------------------------------------------
// K6: single-pass softmax aggregation over bf16 h, 4-deep software pipeline.
// 4 B edge records (src | bf16(w)<<16). packout: write packed bf16 (layer 0
// intermediate) vs fp32 (final output).
__global__ __launch_bounds__(256, 8) void kaggr3(
        const uint4* __restrict__ h, const float* __restrict__ ssrc,
        const float* __restrict__ sdst, const int* __restrict__ rowptr,
        const unsigned int* __restrict__ edges, const float* __restrict__ ce4,
        const float* __restrict__ bias, float* __restrict__ out,
        uint4* __restrict__ outb, int packout, int n) {
    int t = threadIdx.x;
    int node = blockIdx.x * 4 + (t >> 6);
    if (node >= n) return;
    int l64 = t & 63;
    int ll = l64 & 15;
    int g  = l64 >> 4;
    int head = ll >> 2;

    int start = rowptr[node], end = rowptr[node + 1];
    float sd = sdst[node * 4 + head];
    float ce = ce4[head];

    float a0=0.f,a1=0.f,a2=0.f,a3=0.f,a4=0.f,a5=0.f,a6=0.f,a7=0.f;
    float se = 0.f;

    int i = start + g;
    for (; i + 12 < end; i += 16) {
        unsigned int er[4];
#pragma unroll
        for (int u = 0; u < 4; u++) er[u] = edges[i + 4 * u];
        float ssv[4]; uint4 U[4];
#pragma unroll
        for (int u = 0; u < 4; u++) {
            int sidx = er[u] & 0xffff;
            ssv[u] = ssrc[sidx * 4 + head];
            U[u] = h[(size_t)sidx * 16 + ll];
        }
#pragma unroll
        for (int u = 0; u < 4; u++) {
            float wv = __uint_as_float(er[u] & 0xffff0000u);
            float l = ssv[u] + sd + wv * ce;
            l = fmaxf(l, 0.2f * l);
            float e = __expf(fminf(l, 80.f));
            float h0 = __uint_as_float(U[u].x << 16);
            float h1 = __uint_as_float(U[u].x & 0xffff0000u);
            float h2 = __uint_as_float(U[u].y << 16);
            float h3 = __uint_as_float(U[u].y & 0xffff0000u);
            float h4 = __uint_as_float(U[u].z << 16);
            float h5 = __uint_as_float(U[u].z & 0xffff0000u);
            float h6 = __uint_as_float(U[u].w << 16);
            float h7 = __uint_as_float(U[u].w & 0xffff0000u);
            se += e;
            a0 = fmaf(e, h0, a0); a1 = fmaf(e, h1, a1);
            a2 = fmaf(e, h2, a2); a3 = fmaf(e, h3, a3);
            a4 = fmaf(e, h4, a4); a5 = fmaf(e, h5, a5);
            a6 = fmaf(e, h6, a6); a7 = fmaf(e, h7, a7);
        }
    }
    for (; i < end; i += 4) {
        unsigned int er = edges[i];
        int sidx = er & 0xffff;
        float ss = ssrc[sidx * 4 + head];
        uint4 U = h[(size_t)sidx * 16 + ll];
        float wv = __uint_as_float(er & 0xffff0000u);
        float l = ss + sd + wv * ce;
        l = fmaxf(l, 0.2f * l);
        float e = __expf(fminf(l, 80.f));
        float h0 = __uint_as_float(U.x << 16);
        float h1 = __uint_as_float(U.x & 0xffff0000u);
        float h2 = __uint_as_float(U.y << 16);
        float h3 = __uint_as_float(U.y & 0xffff0000u);
        float h4 = __uint_as_float(U.z << 16);
        float h5 = __uint_as_float(U.z & 0xffff0000u);
        float h6 = __uint_as_float(U.w << 16);
        float h7 = __uint_as_float(U.w & 0xffff0000u);
        se += e;
        a0 = fmaf(e, h0, a0); a1 = fmaf(e, h1, a1);
        a2 = fmaf(e, h2, a2); a3 = fmaf(e, h3, a3);
        a4 = fmaf(e, h4, a4); a5 = fmaf(e, h5, a5);
        a6 = fmaf(e, h6, a6); a7 = fmaf(e, h7, a7);
    }
#pragma unroll
    for (int off = 16; off < 64; off <<= 1) {
        a0 += __shfl_xor(a0, off); a1 += __shfl_xor(a1, off);
        a2 += __shfl_xor(a2, off); a3 += __shfl_xor(a3, off);
        a4 += __shfl_xor(a4, off); a5 += __shfl_xor(a5, off);
        a6 += __shfl_xor(a6, off); a7 += __shfl_xor(a7, off);
        se += __shfl_xor(se, off);
    }
    if (g == 0) {
        float inv = 1.f / (se + 1e-16f);
        const float4* bp = (const float4*)(bias + ll * 8);
        float4 b0 = bp[0], b1 = bp[1];
        float o0 = a0 * inv + b0.x, o1 = a1 * inv + b0.y;
        float o2 = a2 * inv + b0.z, o3 = a3 * inv + b0.w;
        float o4 = a4 * inv + b1.x, o5 = a5 * inv + b1.y;
        float o6 = a6 * inv + b1.z, o7 = a7 * inv + b1.w;
        if (packout) {
            outb[(size_t)node * 16 + ll] =
                make_uint4(pack_bf16x2(o0, o1), pack_bf16x2(o2, o3),
                           pack_bf16x2(o4, o5), pack_bf16x2(o6, o7));
        } else {
            float4* orow = (float4*)(out + (size_t)node * CN + ll * 8);
            orow[0] = make_float4(o0, o1, o2, o3);
            orow[1] = make_float4(o4, o5, o6, o7);
        }
    }
}

// ---------------------------------------------------------------------------
extern "C" void kernel_launch(void* const* d_in, const int* in_sizes, int n_in,
                              void* d_out, int out_size, void* d_ws, size_t ws_size,
                              hipStream_t stream) {
    const float* x  = (const float*)d_in[0];
    const int*   ei = (const int*)d_in[1];
    const float* ew = (const float*)d_in[2];
    int N_ = in_sizes[0] / CN;
    int E_ = in_sizes[2];
    int EP = E_ + N_;
    int NB = (N_ + 255) >> BSH;
    int NT = (N_ + 63) / 64;

    size_t off = 0;
    auto alloc = [&](size_t bytes) -> void* {
        void* p = (char*)d_ws + off;
        off += (bytes + 255) & ~(size_t)255;
        return p;
    };
    unsigned int* hbuf = (unsigned int*)alloc((size_t)N_ * 64 * 4);  // bf16x2 packed
    uint4* x1b     = (uint4*)alloc((size_t)N_ * 64 * 4);             // bf16 x1
    float* ssrc    = (float*)alloc((size_t)N_ * 4 * 4);
    float* sdst    = (float*)alloc((size_t)N_ * 4 * 4);
    int*   rowptr  = (int*)alloc((size_t)(N_ + 1) * 4);
    unsigned int* edges = (unsigned int*)alloc((size_t)EP * 4);
    int2*  inter   = (int2*)alloc((size_t)256 << CAPSH << 3);        // 16.8 MB
    int*   cursors = (int*)alloc((size_t)256 * 16 * 4);              // line-strided
    int*   ewmaxArr= (int*)alloc((size_t)NBLK * 4);
    unsigned short* wt0 = (unsigned short*)alloc((size_t)CN * CN * 2);
    unsigned short* wt1 = (unsigned short*)alloc((size_t)CN * CN * 2);
    float* cedge   = (float*)alloc(256);

    hipMemsetAsync(cursors, 0, (size_t)256 * 16 * 4, stream);

    const int* srcs = ei;
    const int* dsts = ei + E_;

    kprep<<<NBLK + 3, 256, 0, stream>>>(srcs, dsts, ew, E_, N_, cursors, ewmaxArr,
                                        inter,
                                        (const float*)d_in[5], (const float*)d_in[13],
                                        (const float*)d_in[6], (const float*)d_in[9],
                                        (const float*)d_in[14], (const float*)d_in[17],
                                        wt0, wt1, cedge);

    // merged: kbC (blocks [0,NB)) + layer-0 GN/GEMM (blocks [NB, NB+NT))
    kbCgn<<<NB + NT, 256, 0, stream>>>(
        cursors, ewmaxArr, inter, edges, rowptr, N_, NB, EP,
        x, (const float*)d_in[3], (const float*)d_in[4], wt0,
        (const float*)d_in[7], (const float*)d_in[8],
        hbuf, ssrc, sdst);

    kaggr3<<<(N_ + 3) / 4, 256, 0, stream>>>(
        (const uint4*)hbuf, ssrc, sdst, rowptr, edges, cedge,
        (const float*)d_in[10], (float*)d_out, x1b, 1, N_);

    kgn_gemm7<<<NT, 256, 0, stream>>>(
        x, (const uint4*)x1b, 1, (const float*)d_in[11], (const float*)d_in[12],
        wt1, (const float*)d_in[15], (const float*)d_in[16],
        hbuf, ssrc, sdst, N_);
    kaggr3<<<(N_ + 3) / 4, 256, 0, stream>>>(
        (const uint4*)hbuf, ssrc, sdst, rowptr, edges, cedge + 4,
        (const float*)d_in[18], (float*)d_out, x1b, 0, N_);
}